// Round 14
// baseline (25.518 us; speedup 1.0000x reference)
//
#include <hip/hip_runtime.h>

// OuterProductMean on MI355X (gfx950).
// out[i,j,p] = b2[p] + sum_{c,d} W2[p, c*32+d] * x[i,d] * x[j,c],  x = seq@W1^T + b1.
// Factored: Y[i][c][p] = sum_d W2[p][c*32+d] * x[i][d]  (f16, 2 MB scratch)
//           out[i,j,p] = b2[p] + sum_c x[j,c] * Y[i][c][p]
// TWO kernels:
//  k_front: fused x + Y. Phase A = x via MFMA, operands staged in LDS
//           (R9/R11 lesson: frag operands from strided GLOBAL are latency death).
//           W2 staged by waves 2-3 CONCURRENT with phase A (waves 0-1).
//           Phase B = proven W2-slice FMA.
//  k_outer: MFMA + wave-private transpose epilogue; out stores are
//           NON-TEMPORAL dwordx4 (bypass L2 thrash: 64MB stream would evict
//           the Ygh/xgh read set); lgkm-only barriers; Y double-buffer.
// Floor: 67 MB output write ~10.6 us.

static constexpr int LL  = 512;
static constexpr int IND = 256;
static constexpr int DM  = 32;   // DIM_MSA
static constexpr int PD  = 64;   // PAIR_DIM

typedef _Float16 f16x4 __attribute__((ext_vector_type(4)));
typedef _Float16 f16x8 __attribute__((ext_vector_type(8)));
typedef float    f32x4  __attribute__((ext_vector_type(4)));
typedef float    f32x16 __attribute__((ext_vector_type(16)));

// LDS-only barrier: order ds ops across waves WITHOUT draining global stores.
#define LGKM_BARRIER() do { \
    asm volatile("s_waitcnt lgkmcnt(0)" ::: "memory"); \
    __builtin_amdgcn_s_barrier(); \
  } while (0)

__device__ __forceinline__ f16x4 cvt4(const float4 v) {
  f16x4 r;
  r[0] = (_Float16)v.x; r[1] = (_Float16)v.y;
  r[2] = (_Float16)v.z; r[3] = (_Float16)v.w;
  return r;
}

// ---------------- k_front: fused proj1 (MFMA from LDS) + Y (FMA).
// Grid 256 = (8 i-chunks of 64 rows) x (32 c). 256 threads.
// Frag mapping (mfma_f32_32x32x16_f16, verified R6/R11):
//   A[m][k]: m=lane&31 (seq row), k=ks*16+(lane>>5)*8+e
//   B[k][n]: n=lane&31 (W1 row = output d), same k
//   D: col(n)=lane&31, row(m)=(r&3)+8*(r>>2)+4*(lane>>5)
static constexpr int SP = 264;  // f16 row stride: 528B = 33 x 16B -> rows walk banks

__global__ __launch_bounds__(256) void k_front(const float* __restrict__ seq,
                                               const float* __restrict__ W1,
                                               const float* __restrict__ b1,
                                               const float* __restrict__ W2,
                                               _Float16* __restrict__ xgh,
                                               _Float16* __restrict__ Ygh) {
  __shared__ __align__(16) _Float16 seqs[64 * SP];  // 33 KB
  __shared__ __align__(16) _Float16 w1s[32 * SP];   // 16.5 KB
  __shared__ __align__(16) float ws2[64][36];       //  9 KB
  __shared__ __align__(16) float xs[64][36];        //  9 KB
  const int c     = blockIdx.x & 31;
  const int ibase = (blockIdx.x >> 5) * 64;
  const int t     = threadIdx.x;

  // stage seq chunk [64][256] -> f16 (coalesced: consecutive float4 per lane)
#pragma unroll
  for (int k = 0; k < 16; ++k) {
    const int f = t + k * 256;            // float4 idx over 64x64
    const int row = f >> 6, c4 = f & 63;
    const float4 v = *(const float4*)(seq + (size_t)(ibase + row) * IND + c4 * 4);
    *(f16x4*)&seqs[row * SP + c4 * 4] = cvt4(v);
  }
  // stage W1 [32][256] -> f16
#pragma unroll
  for (int k = 0; k < 8; ++k) {
    const int f = t + k * 256;            // float4 idx over 32x64
    const int row = f >> 6, c4 = f & 63;
    const float4 v = *(const float4*)(W1 + (size_t)row * IND + c4 * 4);
    *(f16x4*)&w1s[row * SP + c4 * 4] = cvt4(v);
  }
  __syncthreads();

  // phase A (waves 0,1): x[ibase + w*32 .. +32][0..32] via 16 chained MFMAs.
  // Frag reads conflict-free: 16B-unit bank = (row + 2*ks + lh) & 31.
  // CONCURRENTLY waves 2,3 stage the W2 slice (needed only in phase B).
  const int w = t >> 6, lane = t & 63, l31 = lane & 31, lh = lane >> 5;
  if (w < 2) {
    const _Float16* arow = &seqs[(w * 32 + l31) * SP + lh * 8];
    const _Float16* brow = &w1s[l31 * SP + lh * 8];
    f32x16 acc = {};
#pragma unroll
    for (int ks = 0; ks < 16; ++ks) {
      const f16x8 af = *(const f16x8*)(arow + ks * 16);
      const f16x8 bf = *(const f16x8*)(brow + ks * 16);
      acc = __builtin_amdgcn_mfma_f32_32x32x16_f16(af, bf, acc, 0, 0, 0);
    }
    const float bias1 = b1[l31];
#pragma unroll
    for (int r = 0; r < 16; ++r) {
      const int mrow = (r & 3) + 8 * (r >> 2) + 4 * lh;
      const float v = acc[r] + bias1;
      xs[w * 32 + mrow][l31] = v;
      if (c == 0) xgh[(size_t)(ibase + w * 32 + mrow) * DM + l31] = (_Float16)v;
    }
  } else {
    const int t2 = t - 128;
#pragma unroll
    for (int k = 0; k < 4; ++k) {
      const int idx = t2 + k * 128;       // 0..511 float4s over [64 p][8 d4]
      const int p = idx >> 3, d4 = idx & 7;
      const float4 v = *(const float4*)(W2 + (size_t)p * (DM * DM) + c * DM + d4 * 4);
      *(float4*)&ws2[p][d4 * 4] = v;
    }
  }
  __syncthreads();

  // phase B (proven): Y[i][c][p] = sum_d ws2[p][d] * xs[i][d]
  {
    const int p  = t & 63;
    const int ig = t >> 6;
    float wv[DM];
#pragma unroll
    for (int q = 0; q < 8; ++q) {
      const float4 v = *(const float4*)&ws2[p][q * 4];
      wv[q * 4 + 0] = v.x; wv[q * 4 + 1] = v.y;
      wv[q * 4 + 2] = v.z; wv[q * 4 + 3] = v.w;
    }
#pragma unroll
    for (int il = 0; il < 16; ++il) {
      const int row = ig * 16 + il;
      float a = 0.f;
#pragma unroll
      for (int q = 0; q < 8; ++q) {
        const float4 v = *(const float4*)&xs[row][q * 4];
        a = fmaf(wv[q * 4 + 0], v.x, a);
        a = fmaf(wv[q * 4 + 1], v.y, a);
        a = fmaf(wv[q * 4 + 2], v.z, a);
        a = fmaf(wv[q * 4 + 3], v.w, a);
      }
      Ygh[((size_t)(ibase + row) * DM + c) * PD + p] = (_Float16)a;  // coalesced
    }
  }
}

// ---------------- k_outer: MFMA + wave-private LDS-transpose epilogue.
// Block = 128 thr (2 waves), 2 i-tiles (i0, i0+256) x 128 j x 64 p.
// D layout: col(p)=lane&31, row(j)=(reg&3)+8*(reg>>2)+4*(lane>>5)  [verified R6].
// out stores are NON-TEMPORAL (streaming 64MB must not evict the read set).
static constexpr int XPAD = 40;  // f16 row stride 80B (16B-aligned b128 reads)

__global__ __launch_bounds__(128, 3) void k_outer(const _Float16* __restrict__ xgh,
                                                  const _Float16* __restrict__ Ygh,
                                                  const float* __restrict__ b2,
                                                  float* __restrict__ out) {
  __shared__ __align__(16) _Float16 xbs[128 * XPAD];  // 10 KB: [j_local][c]
  __shared__ __align__(16) _Float16 ybs[2 * DM * PD]; // 2 x 4 KB: [c][p]
  __shared__ __align__(16) float    obuf[2][32 * 32]; // per-wave 4 KB
  const int q  = blockIdx.x & 3;       // j-quarter
  const int i0 = blockIdx.x >> 2;      // first i; second is i0+256
  const int t  = threadIdx.x;

  const int lane = t & 63;
  const int w    = t >> 6;        // p-half (0/1)
  const int l31  = lane & 31;
  const int lh   = lane >> 5;
  const int pn   = w * 32 + l31;  // this lane's p (n index)
  float* const obufW = &obuf[w][0];
  const float4 bias4 = *(const float4*)(b2 + w * 32 + (lane & 7) * 4);

  // stage Ygh[i0] into ybs[0] (issued first: B-frags depend on it)
  {
    const f16x8* ys = (const f16x8*)(Ygh + (size_t)i0 * (DM * PD));
    *(f16x8*)&ybs[t * 8]        = ys[t];
    *(f16x8*)&ybs[1024 + t * 8] = ys[128 + t];
  }
  // stage x rows (row j = t): 64B per thread, coalesced; q-dependent only
  {
    const f16x8* src = (const f16x8*)(xgh + (size_t)(q * 128 + t) * DM);
    _Float16* dst = &xbs[t * XPAD];
    *(f16x8*)(dst)      = src[0];
    *(f16x8*)(dst + 8)  = src[1];
    *(f16x8*)(dst + 16) = src[2];
    *(f16x8*)(dst + 24) = src[3];
  }
  LGKM_BARRIER();

  // issue-early: Ygh[i1] global loads in flight across tile-0 compute
  const f16x8* ys1 = (const f16x8*)(Ygh + (size_t)(i0 + 256) * (DM * PD));
  const f16x8 n0 = ys1[t];
  const f16x8 n1 = ys1[128 + t];

  auto process = [&](int i, const _Float16* __restrict__ yb) {
    // B frags: one-time scattered u16 gather (2-way bank alias = free)
    f16x8 b0, b1;
#pragma unroll
    for (int e = 0; e < 8; ++e) {
      b0[e] = yb[(lh * 8 + e) * PD + pn];
      b1[e] = yb[(16 + lh * 8 + e) * PD + pn];
    }
    const size_t orow0 = ((size_t)i * LL + q * 128) * PD;
#pragma unroll
    for (int jt = 0; jt < 4; ++jt) {
      const int ai = (jt * 32 + l31) * XPAD + lh * 8;
      const f16x8 a0 = *(const f16x8*)&xbs[ai];
      const f16x8 a1 = *(const f16x8*)&xbs[ai + 16];
      f32x16 acc = {};
      acc = __builtin_amdgcn_mfma_f32_32x32x16_f16(a0, b0, acc, 0, 0, 0);
      acc = __builtin_amdgcn_mfma_f32_32x32x16_f16(a1, b1, acc, 0, 0, 0);
      // wave-private transpose: scatter (banks = l31, 2-way max)
#pragma unroll
      for (int r = 0; r < 16; ++r) {
        const int row = (r & 3) + 8 * (r >> 2) + 4 * lh;  // j within subtile
        obufW[row * 32 + l31] = acc[r];
      }
      // intra-wave readback (compiler orders via lgkmcnt) + nt dense stores
#pragma unroll
      for (int k = 0; k < 4; ++k) {
        const int idx = lane + k * 64;           // float4 idx 0..255
        const int row = idx >> 3, pseg = idx & 7;
        const f32x4 ob = *(const f32x4*)&obufW[idx * 4];
        f32x4 v;
        v.x = ob.x + bias4.x; v.y = ob.y + bias4.y;
        v.z = ob.z + bias4.z; v.w = ob.w + bias4.w;
        f32x4* dst = (f32x4*)(out + orow0 + (size_t)(jt * 32 + row) * PD +
                              w * 32 + pseg * 4);
        __builtin_nontemporal_store(v, dst);
      }
    }
  };

  process(i0, ybs);

  // write-late: commit prefetched Y[i1]
  *(f16x8*)&ybs[2048 + t * 8]        = n0;
  *(f16x8*)&ybs[2048 + 1024 + t * 8] = n1;
  LGKM_BARRIER();

  process(i0 + 256, ybs + 2048);
}

extern "C" void kernel_launch(void* const* d_in, const int* in_sizes, int n_in,
                              void* d_out, int out_size, void* d_ws, size_t ws_size,
                              hipStream_t stream) {
  const float* seq = (const float*)d_in[0];
  const float* W1  = (const float*)d_in[1];
  const float* b1  = (const float*)d_in[2];
  const float* W2  = (const float*)d_in[3];
  const float* b2  = (const float*)d_in[4];
  float* out = (float*)d_out;

  // ws layout: xgh f16[512*32] | Ygh f16[512*32*64]  => ~2.1 MB
  _Float16* xgh = (_Float16*)d_ws;
  _Float16* Ygh = xgh + LL * DM;

  k_front<<<256, 256, 0, stream>>>(seq, W1, b1, W2, xgh, Ygh);
  k_outer<<<LL * 2, 128, 0, stream>>>(xgh, Ygh, b2, out);
}

// Round 15
// 22.350 us; speedup vs baseline: 1.1418x; 1.1418x over previous
//
#include <hip/hip_runtime.h>

// OuterProductMean on MI355X (gfx950).
// out[i,j,p] = b2[p] + sum_{c,d} W2[p, c*32+d] * x[i,d] * x[j,c],  x = seq@W1^T + b1.
// Factored: Y[i][c][p] = sum_d W2[p][c*32+d] * x[i][d]  (f16, 2 MB scratch)
//           out[i,j,p] = b2[p] + sum_c x[j,c] * Y[i][c][p]
// TWO kernels:
//  k_front: ALL-MFMA. Phase A: x = seq@W1^T (LDS-staged frags, R13-proven).
//           Phase B: Y[64i][64p] = x@W2slice^T as 8 mfma across 4 waves
//           (replaces the 128-b128-reads/thread VALU version -- that LDS
//           issue serialization was k_front's cost). x/W2 in [row][40] f16
//           LDS (k_outer's proven conflict-free stride).
//  k_outer: BYTE-IDENTICAL to R13 (plain dwordx4 stores -- R14's nontemporal
//           experiment REGRESSED; L2-thrash theory refuted).
// Floor: 67 MB output write ~10.6 us.

static constexpr int LL  = 512;
static constexpr int IND = 256;
static constexpr int DM  = 32;   // DIM_MSA
static constexpr int PD  = 64;   // PAIR_DIM

typedef _Float16 f16x4 __attribute__((ext_vector_type(4)));
typedef _Float16 f16x8 __attribute__((ext_vector_type(8)));
typedef float    f32x16 __attribute__((ext_vector_type(16)));

// LDS-only barrier: order ds ops across waves WITHOUT draining global stores.
#define LGKM_BARRIER() do { \
    asm volatile("s_waitcnt lgkmcnt(0)" ::: "memory"); \
    __builtin_amdgcn_s_barrier(); \
  } while (0)

__device__ __forceinline__ f16x4 cvt4(const float4 v) {
  f16x4 r;
  r[0] = (_Float16)v.x; r[1] = (_Float16)v.y;
  r[2] = (_Float16)v.z; r[3] = (_Float16)v.w;
  return r;
}

// ---------------- k_front: fused proj1 (MFMA) + Y (MFMA).
// Grid 256 = (8 i-chunks of 64 rows) x (32 c). 256 threads.
// Frag mapping (mfma_f32_32x32x16_f16, verified R6/R11/R13):
//   A[m][k]: m=lane&31, k=ks*16+(lane>>5)*8+e   (row-contiguous LDS read)
//   B[k][n]: n=lane&31, same k                  (row-contiguous LDS read)
//   D: col(n)=lane&31, row(m)=(r&3)+8*(r>>2)+4*(lane>>5)
static constexpr int SP = 264;  // f16 stride for seq/W1 staging (33x16B)
static constexpr int XP = 40;   // f16 stride for x/W2 tiles (k_outer-proven)

__global__ __launch_bounds__(256) void k_front(const float* __restrict__ seq,
                                               const float* __restrict__ W1,
                                               const float* __restrict__ b1,
                                               const float* __restrict__ W2,
                                               _Float16* __restrict__ xgh,
                                               _Float16* __restrict__ Ygh) {
  __shared__ __align__(16) _Float16 seqs[64 * SP];  // 33 KB
  __shared__ __align__(16) _Float16 w1s[32 * SP];   // 16.5 KB
  __shared__ __align__(16) _Float16 w2h[64 * XP];   //  5 KB  [p][d]
  __shared__ __align__(16) _Float16 xh[64 * XP];    //  5 KB  [i][d]
  const int c     = blockIdx.x & 31;
  const int ibase = (blockIdx.x >> 5) * 64;
  const int t     = threadIdx.x;

  // stage seq chunk [64][256] -> f16 (coalesced)
#pragma unroll
  for (int k = 0; k < 16; ++k) {
    const int f = t + k * 256;            // float4 idx over 64x64
    const int row = f >> 6, c4 = f & 63;
    const float4 v = *(const float4*)(seq + (size_t)(ibase + row) * IND + c4 * 4);
    *(f16x4*)&seqs[row * SP + c4 * 4] = cvt4(v);
  }
  // stage W1 [32][256] -> f16
#pragma unroll
  for (int k = 0; k < 8; ++k) {
    const int f = t + k * 256;
    const int row = f >> 6, c4 = f & 63;
    const float4 v = *(const float4*)(W1 + (size_t)row * IND + c4 * 4);
    *(f16x4*)&w1s[row * SP + c4 * 4] = cvt4(v);
  }
  // stage W2 slice [64 p][32 d] -> f16, stride 40
#pragma unroll
  for (int k = 0; k < 2; ++k) {
    const int idx = t + k * 256;          // 0..511 float4s
    const int p = idx >> 3, d4 = idx & 7;
    const float4 v = *(const float4*)(W2 + (size_t)p * (DM * DM) + c * DM + d4 * 4);
    *(f16x4*)&w2h[p * XP + d4 * 4] = cvt4(v);
  }
  __syncthreads();

  const int w = t >> 6, lane = t & 63, l31 = lane & 31, lh = lane >> 5;

  // phase A (waves 0,1): x[ibase + w*32 .. +32][0..32] via 16 chained MFMAs.
  if (w < 2) {
    const _Float16* arow = &seqs[(w * 32 + l31) * SP + lh * 8];
    const _Float16* brow = &w1s[l31 * SP + lh * 8];
    f32x16 acc = {};
#pragma unroll
    for (int ks = 0; ks < 16; ++ks) {
      const f16x8 af = *(const f16x8*)(arow + ks * 16);
      const f16x8 bf = *(const f16x8*)(brow + ks * 16);
      acc = __builtin_amdgcn_mfma_f32_32x32x16_f16(af, bf, acc, 0, 0, 0);
    }
    const float bias1 = b1[l31];
#pragma unroll
    for (int r = 0; r < 16; ++r) {
      const int mrow = w * 32 + (r & 3) + 8 * (r >> 2) + 4 * lh;
      const float v = acc[r] + bias1;
      xh[mrow * XP + l31] = (_Float16)v;                 // u16 scatter, cheap
      if (c == 0) xgh[(size_t)(ibase + mrow) * DM + l31] = (_Float16)v;
    }
  }
  __syncthreads();

  // phase B (all 4 waves): Y[64 i][64 p] = xh[64][32] @ w2h[64][32]^T
  // wave w -> (ih = w>>1, ph = w&1): one 32x32 tile, K=32 as 2 chained MFMAs.
  {
    const int ih = w >> 1, ph = w & 1;
    const _Float16* arow = &xh[(ih * 32 + l31) * XP + lh * 8];
    const _Float16* brow = &w2h[(ph * 32 + l31) * XP + lh * 8];
    f32x16 acc = {};
    {
      const f16x8 a0 = *(const f16x8*)(arow);
      const f16x8 b0 = *(const f16x8*)(brow);
      acc = __builtin_amdgcn_mfma_f32_32x32x16_f16(a0, b0, acc, 0, 0, 0);
      const f16x8 a1 = *(const f16x8*)(arow + 16);
      const f16x8 b1 = *(const f16x8*)(brow + 16);
      acc = __builtin_amdgcn_mfma_f32_32x32x16_f16(a1, b1, acc, 0, 0, 0);
    }
    // D: col(p)=l31, row(i)=(r&3)+8*(r>>2)+4*lh. Store f16 to Ygh[i][c][p].
    _Float16* ybase = Ygh + ((size_t)ibase * DM + c) * PD + ph * 32 + l31;
#pragma unroll
    for (int r = 0; r < 16; ++r) {
      const int irow = ih * 32 + (r & 3) + 8 * (r >> 2) + 4 * lh;
      ybase[(size_t)irow * (DM * PD)] = (_Float16)acc[r];  // 2x64B seg / wave-inst
    }
  }
}

// ---------------- k_outer: MFMA + wave-private LDS-transpose epilogue.
// (BYTE-IDENTICAL to R13.)
// Block = 128 thr (2 waves), 2 i-tiles (i0, i0+256) x 128 j x 64 p.
// D layout: col(p)=lane&31, row(j)=(reg&3)+8*(reg>>2)+4*(lane>>5)  [verified R6].
static constexpr int XPAD = 40;  // f16 row stride 80B (16B-aligned b128 reads)

__global__ __launch_bounds__(128, 3) void k_outer(const _Float16* __restrict__ xgh,
                                                  const _Float16* __restrict__ Ygh,
                                                  const float* __restrict__ b2,
                                                  float* __restrict__ out) {
  __shared__ __align__(16) _Float16 xbs[128 * XPAD];  // 10 KB: [j_local][c]
  __shared__ __align__(16) _Float16 ybs[2 * DM * PD]; // 2 x 4 KB: [c][p]
  __shared__ __align__(16) float    obuf[2][32 * 32]; // per-wave 4 KB
  const int q  = blockIdx.x & 3;       // j-quarter
  const int i0 = blockIdx.x >> 2;      // first i; second is i0+256
  const int t  = threadIdx.x;

  const int lane = t & 63;
  const int w    = t >> 6;        // p-half (0/1)
  const int l31  = lane & 31;
  const int lh   = lane >> 5;
  const int pn   = w * 32 + l31;  // this lane's p (n index)
  float* const obufW = &obuf[w][0];
  const float4 bias4 = *(const float4*)(b2 + w * 32 + (lane & 7) * 4);

  // stage x rows (row j = t): 64B per thread, coalesced; q-dependent only
  {
    const f16x8* src = (const f16x8*)(xgh + (size_t)(q * 128 + t) * DM);
    _Float16* dst = &xbs[t * XPAD];
    *(f16x8*)(dst)      = src[0];
    *(f16x8*)(dst + 8)  = src[1];
    *(f16x8*)(dst + 16) = src[2];
    *(f16x8*)(dst + 24) = src[3];
  }
  // stage Ygh[i0] into ybs[0]
  {
    const f16x8* ys = (const f16x8*)(Ygh + (size_t)i0 * (DM * PD));
    *(f16x8*)&ybs[t * 8]        = ys[t];
    *(f16x8*)&ybs[1024 + t * 8] = ys[128 + t];
  }
  LGKM_BARRIER();

  // issue-early: Ygh[i1] global loads in flight across tile-0 compute
  const f16x8* ys1 = (const f16x8*)(Ygh + (size_t)(i0 + 256) * (DM * PD));
  const f16x8 n0 = ys1[t];
  const f16x8 n1 = ys1[128 + t];

  auto process = [&](int i, const _Float16* __restrict__ yb) {
    // B frags: one-time scattered u16 gather (2-way bank alias = free)
    f16x8 b0, b1;
#pragma unroll
    for (int e = 0; e < 8; ++e) {
      b0[e] = yb[(lh * 8 + e) * PD + pn];
      b1[e] = yb[(16 + lh * 8 + e) * PD + pn];
    }
    const size_t orow0 = ((size_t)i * LL + q * 128) * PD;
#pragma unroll
    for (int jt = 0; jt < 4; ++jt) {
      const int ai = (jt * 32 + l31) * XPAD + lh * 8;
      const f16x8 a0 = *(const f16x8*)&xbs[ai];
      const f16x8 a1 = *(const f16x8*)&xbs[ai + 16];
      f32x16 acc = {};
      acc = __builtin_amdgcn_mfma_f32_32x32x16_f16(a0, b0, acc, 0, 0, 0);
      acc = __builtin_amdgcn_mfma_f32_32x32x16_f16(a1, b1, acc, 0, 0, 0);
      // wave-private transpose: scatter (banks = l31, 2-way max)
#pragma unroll
      for (int r = 0; r < 16; ++r) {
        const int row = (r & 3) + 8 * (r >> 2) + 4 * lh;  // j within subtile
        obufW[row * 32 + l31] = acc[r];
      }
      // intra-wave readback (compiler orders via lgkmcnt) + dense stores
#pragma unroll
      for (int k = 0; k < 4; ++k) {
        const int idx = lane + k * 64;           // float4 idx 0..255
        const int row = idx >> 3, pseg = idx & 7;
        float4 v = *(const float4*)&obufW[idx * 4];
        v.x += bias4.x; v.y += bias4.y; v.z += bias4.z; v.w += bias4.w;
        *(float4*)(out + orow0 + (size_t)(jt * 32 + row) * PD + w * 32 + pseg * 4) = v;
      }
    }
  };

  process(i0, ybs);

  // write-late: commit prefetched Y[i1]
  *(f16x8*)&ybs[2048 + t * 8]        = n0;
  *(f16x8*)&ybs[2048 + 1024 + t * 8] = n1;
  LGKM_BARRIER();

  process(i0 + 256, ybs + 2048);
}

extern "C" void kernel_launch(void* const* d_in, const int* in_sizes, int n_in,
                              void* d_out, int out_size, void* d_ws, size_t ws_size,
                              hipStream_t stream) {
  const float* seq = (const float*)d_in[0];
  const float* W1  = (const float*)d_in[1];
  const float* b1  = (const float*)d_in[2];
  const float* W2  = (const float*)d_in[3];
  const float* b2  = (const float*)d_in[4];
  float* out = (float*)d_out;

  // ws layout: xgh f16[512*32] | Ygh f16[512*32*64]  => ~2.1 MB
  _Float16* xgh = (_Float16*)d_ws;
  _Float16* Ygh = xgh + LL * DM;

  k_front<<<256, 256, 0, stream>>>(seq, W1, b1, W2, xgh, Ygh);
  k_outer<<<LL * 2, 128, 0, stream>>>(xgh, Ygh, b2, out);
}